// Round 9
// baseline (108.057 us; speedup 1.0000x reference)
//
#include <hip/hip_runtime.h>

#define NIN 64
#define NOUT 64
#define NTO 16
#define HH 192
#define WW 192
#define HO 190
#define WO 190
#define NBLK 2304            // 36 groups (9 tiles x 4 batch) x 64 out channels

__global__ __launch_bounds__(256, 4) void scm_kernel(
    const float* __restrict__ x,
    const float* __restrict__ w,
    const float* __restrict__ bias,
    const int* __restrict__ conn_in,
    float* __restrict__ out)
{
    const int tid = threadIdx.x;
    const int tx = tid & 15;        // col group of 4
    const int ty = tid >> 4;        // row group of 4

    // XCD-aware swizzle (bijective, 2304 % 8 == 0), o-minor: the 64 blocks
    // sharing one x-tile region are contiguous on one XCD's L2.
    const int lid = (blockIdx.x & 7) * (NBLK / 8) + (blockIdx.x >> 3);
    const int o   = lid & 63;
    const int g   = lid >> 6;       // 0..35
    const int tile = g % 9;
    const int b    = g / 9;
    const int i0 = (tile / 3) * 64;
    const int j0 = (tile % 3) * 64;

    // Channel-independent per-thread byte offsets for the 6 patch rows.
    // Row clamp <=191: clamped rows feed only outputs >=190 (discarded).
    // float2 col clamp <=190: substituted values feed only discarded taps.
    const int c0 = j0 + tx * 4;                   // 16B-aligned
    const int c2 = (c0 + 4 > 190) ? 190 : c0 + 4; // 8B-aligned
    int off4[6], off2[6];
    #pragma unroll
    for (int r = 0; r < 6; ++r) {
        int gr = i0 + ty * 4 + r; if (gr > 191) gr = 191;
        off4[r] = (gr * WW + c0) * 4;
        off2[r] = (gr * WW + c2) * 4;
    }

    const char* xb = (const char*)x + (size_t)b * NIN * HH * WW * 4;
    const int kbase = o * NTO;

    float acc[4][4];
    #pragma unroll
    for (int i = 0; i < 4; ++i)
        #pragma unroll
        for (int p = 0; p < 4; ++p) acc[i][p] = 0.f;

    #pragma unroll 1
    for (int t = 0; t < NTO; ++t) {
        const int ci = __builtin_amdgcn_readfirstlane(conn_in[kbase + t]);
        const char* xc = xb + (size_t)ci * (HH * WW * 4);

        // Scalar (lane-uniform) weight loads — lgkm path, independent of vmem.
        float wv9[9];
        #pragma unroll
        for (int q = 0; q < 9; ++q) wv9[q] = w[(kbase + t) * 9 + q];

        // ---- Load the FULL 6x6 patch into named registers, all 12 loads
        // issued back-to-back BEFORE any FMA consumes them (fence below).
        float4 p0 = *(const float4*)(xc + off4[0]);
        float4 p1 = *(const float4*)(xc + off4[1]);
        float4 p2 = *(const float4*)(xc + off4[2]);
        float4 p3 = *(const float4*)(xc + off4[3]);
        float4 p4 = *(const float4*)(xc + off4[4]);
        float4 p5 = *(const float4*)(xc + off4[5]);
        float2 q0 = *(const float2*)(xc + off2[0]);
        float2 q1 = *(const float2*)(xc + off2[1]);
        float2 q2 = *(const float2*)(xc + off2[2]);
        float2 q3 = *(const float2*)(xc + off2[3]);
        float2 q4 = *(const float2*)(xc + off2[4]);
        float2 q5 = *(const float2*)(xc + off2[5]);
        __builtin_amdgcn_sched_barrier(0);   // pin: loads issue first, then compute

        #pragma unroll
        for (int r = 0; r < 6; ++r) {
            const float4 v4 = (r == 0) ? p0 : (r == 1) ? p1 : (r == 2) ? p2
                             : (r == 3) ? p3 : (r == 4) ? p4 : p5;
            const float2 v2 = (r == 0) ? q0 : (r == 1) ? q1 : (r == 2) ? q2
                             : (r == 3) ? q3 : (r == 4) ? q4 : q5;
            const float rowv[6] = {v4.x, v4.y, v4.z, v4.w, v2.x, v2.y};
            #pragma unroll
            for (int i = 0; i < 4; ++i) {
                const int kh = r - i;
                if (kh >= 0 && kh < 3) {
                    #pragma unroll
                    for (int kw = 0; kw < 3; ++kw) {
                        const float wk = wv9[kh * 3 + kw];
                        #pragma unroll
                        for (int p = 0; p < 4; ++p)
                            acc[i][p] = fmaf(wk, rowv[p + kw], acc[i][p]);
                    }
                }
            }
        }
    }

    const float bv = bias[o];
    float* outp = out + (size_t)(b * NOUT + o) * (HO * WO);
    #pragma unroll
    for (int i = 0; i < 4; ++i) {
        const int gi = i0 + ty * 4 + i;
        if (gi < HO) {
            const int gj = j0 + tx * 4;
            float* row = outp + (size_t)gi * WO + gj;
            if (gj + 3 < WO) {
                *(float2*)(row)     = make_float2(acc[i][0] + bv, acc[i][1] + bv);
                *(float2*)(row + 2) = make_float2(acc[i][2] + bv, acc[i][3] + bv);
            } else {
                #pragma unroll
                for (int p = 0; p < 4; ++p)
                    if (gj + p < WO) row[p] = acc[i][p] + bv;
            }
        }
    }
}

extern "C" void kernel_launch(void* const* d_in, const int* in_sizes, int n_in,
                              void* d_out, int out_size, void* d_ws, size_t ws_size,
                              hipStream_t stream) {
    const float* x       = (const float*)d_in[0];
    const float* weight  = (const float*)d_in[1];
    const float* bias    = (const float*)d_in[2];
    const int*   conn_in = (const int*)d_in[3];
    // d_in[4] = conn_out (implicit: k -> k/16)

    dim3 grid(NBLK);
    dim3 block(256);
    scm_kernel<<<grid, block, 0, stream>>>(x, weight, bias, conn_in, (float*)d_out);
}

// Round 10
// 67.700 us; speedup vs baseline: 1.5961x; 1.5961x over previous
//
#include <hip/hip_runtime.h>

#define NIN 64
#define NOUT 64
#define NTO 16
#define HH 192
#define WW 192
#define HO 190
#define WO 190
#define WBUF 5120            // per-wave buffer: 288 main units + 18 halo + 14 pad = 320*16B
#define NBLK 2304            // 36 groups (9 tiles x 4 batch) x 64 out channels

typedef const __attribute__((address_space(1))) void gv_t;
typedef __attribute__((address_space(3))) void lv_t;

__global__ __launch_bounds__(256, 7) void scm_kernel(
    const float* __restrict__ x,
    const float* __restrict__ w,
    const float* __restrict__ bias,
    const int* __restrict__ conn_in,
    float* __restrict__ out)
{
    __shared__ char smem[4 * WBUF];   // 20480 B: 4 waves x single wave-private buffer

    const int tid  = threadIdx.x;
    const int lane = tid & 63;
    const int tx   = tid & 15;       // col group of 4
    const int ty   = tid >> 4;       // row group of 4 (block-wide)
    const int wv   = ty >> 2;        // wave id 0..3 (rows 16*wv .. +15)
    const int lty  = ty & 3;         // row group within wave

    // XCD-aware swizzle (bijective, 2304 % 8 == 0), o-minor for L2 gather reuse.
    const int lid = (blockIdx.x & 7) * (NBLK / 8) + (blockIdx.x >> 3);
    const int o   = lid & 63;
    const int g   = lid >> 6;        // 0..35
    const int tile = g % 9;
    const int b    = g / 9;
    const int i0 = (tile / 3) * 64;
    const int j0 = (tile % 3) * 64;

    // ---- Wave-private LDS layout (5120 B):
    //   [0..4607]    main[18 rows][16 units of 16B]  (256 B row stride)
    //   [4608..4895] halo[18 rows][16B] = global cols j0+64..67
    //   [4896..5119] pad (written, never read)
    // Staged by 5 global_load_lds rounds; physical unit u = s*64+lane.
    // Clamped slots feed only outputs >= row/col 190 (discarded).
    int goff[5];
    #pragma unroll
    for (int s = 0; s < 5; ++s) {
        int u = s * 64 + lane;
        int gr, gc;
        if (u < 288)      { int row = u >> 4; gr = i0 + 16 * wv + row; gc = j0 + 4 * (u & 15); }
        else if (u < 306) { int row = u - 288; gr = i0 + 16 * wv + row;
                            gc = j0 + 64; if (gc > 188) gc = 188; }
        else              { gr = 191; gc = 0; }
        if (gr > 191) gr = 191;
        goff[s] = (gr * WW + gc) * 4;
    }

    // Read offsets (channel-independent):
    //   A = float4 cols tx*4..+3  at main[lr][tx]
    //   B = float2 cols tx*4+4,+5 = first 8B of main[lr][tx+1], or halo[lr] for tx=15
    int offA[6], offB[6];
    #pragma unroll
    for (int r = 0; r < 6; ++r) {
        int lr = lty * 4 + r;
        offA[r] = lr * 256 + tx * 16;
        offB[r] = (tx < 15) ? (lr * 256 + (tx + 1) * 16) : (4608 + lr * 16);
    }

    char* wbase = smem + wv * WBUF;
    const char* xb = (const char*)x + (size_t)b * NIN * HH * WW * 4;
    const int kbase = o * NTO;

    float acc[4][4];
    #pragma unroll
    for (int i = 0; i < 4; ++i)
        #pragma unroll
        for (int p = 0; p < 4; ++p) acc[i][p] = 0.f;

    #pragma unroll 1
    for (int t = 0; t < NTO; ++t) {
        // Our previous-channel ds_reads must have retired before overwriting
        // the wave-private buffer. Wave-local, essentially free.
        asm volatile("s_waitcnt lgkmcnt(0)" ::: "memory");
        __builtin_amdgcn_sched_barrier(0);

        const int ci = __builtin_amdgcn_readfirstlane(conn_in[kbase + t]);
        {
            const char* src = xb + (size_t)ci * (HH * WW * 4);
            #pragma unroll
            for (int s = 0; s < 5; ++s)
                __builtin_amdgcn_global_load_lds((gv_t*)(src + goff[s]),
                                                 (lv_t*)(wbase + s * 1024),
                                                 16, 0, 0);
        }

        // Scalar weight loads overlap the DMA wait.
        float wv9[9];
        #pragma unroll
        for (int q = 0; q < 9; ++q) wv9[q] = w[(kbase + t) * 9 + q];

        asm volatile("s_waitcnt vmcnt(0)" ::: "memory");
        __builtin_amdgcn_sched_barrier(0);

        #pragma unroll
        for (int r = 0; r < 6; ++r) {
            const float4 v4 = *(const float4*)(wbase + offA[r]);
            const float2 v2 = *(const float2*)(wbase + offB[r]);
            const float rowv[6] = {v4.x, v4.y, v4.z, v4.w, v2.x, v2.y};
            #pragma unroll
            for (int i = 0; i < 4; ++i) {
                const int kh = r - i;
                if (kh >= 0 && kh < 3) {
                    #pragma unroll
                    for (int kw = 0; kw < 3; ++kw) {
                        const float wk = wv9[kh * 3 + kw];
                        #pragma unroll
                        for (int p = 0; p < 4; ++p)
                            acc[i][p] = fmaf(wk, rowv[p + kw], acc[i][p]);
                    }
                }
            }
        }
    }

    const float bv = bias[o];
    float* outp = out + (size_t)(b * NOUT + o) * (HO * WO);
    #pragma unroll
    for (int i = 0; i < 4; ++i) {
        const int gi = i0 + ty * 4 + i;
        if (gi < HO) {
            const int gj = j0 + tx * 4;
            float* row = outp + (size_t)gi * WO + gj;
            if (gj + 3 < WO) {
                *(float2*)(row)     = make_float2(acc[i][0] + bv, acc[i][1] + bv);
                *(float2*)(row + 2) = make_float2(acc[i][2] + bv, acc[i][3] + bv);
            } else {
                #pragma unroll
                for (int p = 0; p < 4; ++p)
                    if (gj + p < WO) row[p] = acc[i][p] + bv;
            }
        }
    }
}

extern "C" void kernel_launch(void* const* d_in, const int* in_sizes, int n_in,
                              void* d_out, int out_size, void* d_ws, size_t ws_size,
                              hipStream_t stream) {
    const float* x       = (const float*)d_in[0];
    const float* weight  = (const float*)d_in[1];
    const float* bias    = (const float*)d_in[2];
    const int*   conn_in = (const int*)d_in[3];
    // d_in[4] = conn_out (implicit: k -> k/16)

    dim3 grid(NBLK);
    dim3 block(256);
    scm_kernel<<<grid, block, 0, stream>>>(x, weight, bias, conn_in, (float*)d_out);
}